// Round 3
// baseline (607.484 us; speedup 1.0000x reference)
//
#include <hip/hip_runtime.h>
#include <hip/hip_cooperative_groups.h>
#include <math.h>

namespace cg = cooperative_groups;

// Problem constants (fixed by setup_inputs): N=4, K=11, H=W=256.
#define NB    4
#define KF    11
#define KK    121
#define HH    256
#define WW    256
#define HW    (HH * WW)
#define PADK  5
#define TROWS 12                 // rows staged per block (RPB + KF - 1)
#define TW2   268                // padded tile width, multiple of 4 for b64 align
#define INVD  (1.0f / 255.0f)
#define RPB   2                  // output rows per block
#define GRID1 (NB * HH / RPB)    // 512 blocks = 2 blocks/CU: co-resident

typedef float f2v __attribute__((ext_vector_type(2)));

__device__ __forceinline__ f2v ntload2(const float* p) {
    return __builtin_nontemporal_load((const f2v*)p);
}

// filter_flow pass applied to m1in (staged via LDS tile) and optionally,
// fused, to the analytic grid (FUSE). Writes per-block partial loss.
template <bool FUSE>
__device__ __forceinline__ void pass2_body(
    const float* __restrict__ F, const float* __restrict__ m1in,
    float* __restrict__ m1out, float* __restrict__ presult,
    int n, int h0, int sub, int h, int w0, int t,
    const float* mk0, const float* mk1, float b0,
    float* tile, float* wsum)
{
    // Stage 12-row x 268-col x 2-ch m1in neighborhood into LDS.
    const float* mbase = m1in + (size_t)n * 2 * HW;
    for (int i = t; i < 2 * TROWS * TW2; i += 256) {
        int ch  = i / (TROWS * TW2);
        int rem = i - ch * (TROWS * TW2);
        int r   = rem / TW2;
        int c   = rem - r * TW2;
        int rr  = h0 + r - PADK;
        int cc  = c - PADK;
        float v = 0.0f;
        if (rr >= 0 && rr < HH && cc >= 0 && cc < WW)
            v = mbase[(size_t)ch * HW + rr * WW + cc];
        tile[i] = v;
    }
    __syncthreads();

    const float* fp = F + (size_t)n * KK * HW + (size_t)h * WW + w0;

    float a1x0 = 0, a1y0 = 0, a1x1 = 0, a1y1 = 0;
    float a2x0 = 0, a2y0 = 0, a2x1 = 0, a2y1 = 0;

    for (int ky = 0; ky < KF; ++ky) {
        int rr = h + ky - PADK;
        if (rr < 0 || rr >= HH) continue;     // wave-uniform; tile rows zero anyway
        float yv = (float)rr * INVD;
        const float* fr = fp + (size_t)(ky * KF) * HW;

        // Register-cache this ky's tile span: cols w0..w0+11, both channels.
        const float* tx = tile + (sub + ky) * TW2 + w0;   // 8B-aligned
        const float* ty = tx + TROWS * TW2;
        float cx[12], cy[12];
#pragma unroll
        for (int q = 0; q < 6; ++q) {
            f2v vx = *(const f2v*)(tx + 2 * q);
            f2v vy = *(const f2v*)(ty + 2 * q);
            cx[2 * q] = vx.x; cx[2 * q + 1] = vx.y;
            cy[2 * q] = vy.x; cy[2 * q + 1] = vy.y;
        }

        float s0 = 0, s1 = 0;
#pragma unroll
        for (int kx = 0; kx < KF; ++kx) {
            f2v f = ntload2(fr + (size_t)kx * HW);
            if (FUSE) {
                float u0 = f.x * mk0[kx], u1 = f.y * mk1[kx];
                float xk = b0 + (float)kx * INVD;
                a1x0 = fmaf(u0, xk, a1x0);
                a1x1 = fmaf(u1, xk + INVD, a1x1);
                s0 += u0; s1 += u1;
            }
            a2x0 = fmaf(f.x, cx[kx], a2x0);
            a2x1 = fmaf(f.y, cx[kx + 1], a2x1);
            a2y0 = fmaf(f.x, cy[kx], a2y0);
            a2y1 = fmaf(f.y, cy[kx + 1], a2y1);
        }
        if (FUSE) {
            a1y0 = fmaf(yv, s0, a1y0);
            a1y1 = fmaf(yv, s1, a1y1);
        }
    }

    if (FUSE) {
        f2v ox = {a1x0, a1x1}, oy = {a1y0, a1y1};
        *(f2v*)(m1out + (size_t)n * 2 * HW + (size_t)h * WW + w0) = ox;
        *(f2v*)(m1out + (size_t)n * 2 * HW + HW + (size_t)h * WW + w0) = oy;
    }

    float gx = (float)w0 * INVD, gy = (float)h * INVD;
    float dx0 = gx - a2x0,        dy0 = gy - a2y0;
    float dx1 = gx + INVD - a2x1, dy1 = gy - a2y1;
    float d = sqrtf(dx0 * dx0 + dy0 * dy0) + sqrtf(dx1 * dx1 + dy1 * dy1);

#pragma unroll
    for (int off = 32; off > 0; off >>= 1) d += __shfl_down(d, off, 64);
    if ((t & 63) == 0) wsum[t >> 6] = d;
    __syncthreads();
    if (t == 0) *presult = wsum[0] + wsum[1] + wsum[2] + wsum[3];
}

__global__ __launch_bounds__(256, 2) void fused_kernel(
    const float* __restrict__ FA, const float* __restrict__ FB,
    float* __restrict__ m1A, float* __restrict__ m1B,
    float* __restrict__ partial, float* __restrict__ out)
{
    __shared__ float tile[2 * TROWS * TW2];   // 25.7 KB
    __shared__ float wsum[4];
    cg::grid_group grid = cg::this_grid();

    const int t   = threadIdx.x;
    const int bid = blockIdx.x;
    const int n   = bid / (HH / RPB);
    const int h0  = (bid % (HH / RPB)) * RPB;
    const int sub = t >> 7;
    const int j   = t & 127;
    const int h   = h0 + sub;
    const int w0  = j * 2;

    float mk0[KF], mk1[KF];
#pragma unroll
    for (int kx = 0; kx < KF; ++kx) {
        int c0 = w0 + kx - PADK;
        mk0[kx] = (c0 >= 0 && c0 < WW) ? 1.0f : 0.0f;
        mk1[kx] = (c0 + 1 >= 0 && c0 + 1 < WW) ? 1.0f : 0.0f;
    }
    const float b0 = (float)(w0 - PADK) * INVD;

    // ---- Phase 1: m1A = flow(grid, FA), no LDS needed
    {
        const float* fp = FA + (size_t)n * KK * HW + (size_t)h * WW + w0;
        float ax0 = 0, ay0 = 0, ax1 = 0, ay1 = 0;
        for (int ky = 0; ky < KF; ++ky) {
            int rr = h + ky - PADK;
            if (rr < 0 || rr >= HH) continue;
            float yv = (float)rr * INVD;
            const float* fr = fp + (size_t)(ky * KF) * HW;
            float s0 = 0, s1 = 0;
#pragma unroll
            for (int kx = 0; kx < KF; ++kx) {
                f2v f = ntload2(fr + (size_t)kx * HW);
                float u0 = f.x * mk0[kx], u1 = f.y * mk1[kx];
                float xk = b0 + (float)kx * INVD;
                ax0 = fmaf(u0, xk, ax0);
                ax1 = fmaf(u1, xk + INVD, ax1);
                s0 += u0; s1 += u1;
            }
            ay0 = fmaf(yv, s0, ay0);
            ay1 = fmaf(yv, s1, ay1);
        }
        f2v vx = {ax0, ax1}, vy = {ay0, ay1};
        *(f2v*)(m1A + (size_t)n * 2 * HW + (size_t)h * WW + w0) = vx;
        *(f2v*)(m1A + (size_t)n * 2 * HW + HW + (size_t)h * WW + w0) = vy;
    }

    __threadfence();          // make m1A device-visible across XCDs
    grid.sync();

    // ---- Phase 2: read FB once -> m1B = flow(grid,FB) AND m2A = flow(m1A,FB)
    pass2_body<true>(FB, m1A, m1B, partial + bid,
                     n, h0, sub, h, w0, t, mk0, mk1, b0, tile, wsum);

    __threadfence();          // make m1B + partial[0..511] device-visible
    grid.sync();

    // ---- Phase 3: read FA again -> m2B = flow(m1B,FA)
    pass2_body<false>(FA, m1B, nullptr, partial + GRID1 + bid,
                      n, h0, sub, h, w0, t, mk0, mk1, b0, tile, wsum);

    __threadfence();          // make partial[512..1023] device-visible
    grid.sync();

    // ---- Final reduction on block 0 (wsum reusable: grid.sync synced the block)
    if (bid == 0) {
        float s = partial[t] + partial[t + 256] + partial[t + 512] + partial[t + 768];
#pragma unroll
        for (int off = 32; off > 0; off >>= 1) s += __shfl_down(s, off, 64);
        if ((t & 63) == 0) wsum[t >> 6] = s;
        __syncthreads();
        if (t == 0)
            out[0] = (wsum[0] + wsum[1] + wsum[2] + wsum[3]) *
                     (1.0f / ((float)HW * (float)NB));
    }
}

extern "C" void kernel_launch(void* const* d_in, const int* in_sizes, int n_in,
                              void* d_out, int out_size, void* d_ws, size_t ws_size,
                              hipStream_t stream) {
    const float* FA = (const float*)d_in[0];  // FF_AtoB
    const float* FB = (const float*)d_in[1];  // FF_BtoA
    float* out = (float*)d_out;

    float* m1A = (float*)d_ws;                       // [N,2,H,W] = 2 MB
    float* m1B = m1A + (size_t)NB * 2 * HW;          // [N,2,H,W] = 2 MB
    float* partial = m1B + (size_t)NB * 2 * HW;      // 1024 floats, all rewritten

    void* args[] = {(void*)&FA, (void*)&FB, (void*)&m1A, (void*)&m1B,
                    (void*)&partial, (void*)&out};
    hipLaunchCooperativeKernel((void*)fused_kernel, dim3(GRID1), dim3(256),
                               args, 0, stream);
}

// Round 4
// 315.999 us; speedup vs baseline: 1.9224x; 1.9224x over previous
//
#include <hip/hip_runtime.h>
#include <math.h>

// Problem constants (fixed by setup_inputs): N=4, K=11, H=W=256.
#define NB    4
#define KF    11
#define KK    121
#define HH    256
#define WW    256
#define HW    (HH * WW)
#define PADK  5
#define RPB   2                    // rows per block (1 row per wave)
#define TROWS (RPB + KF - 1)       // 12 tile rows
#define TW2   268                  // padded tile width, multiple of 4 (16B align)
#define INVD  (1.0f / 255.0f)
#define GRID1 (NB * HH / RPB)      // 512 blocks

// Pass 1: m1 = filter_flow(grid, F). 128 thr/block, 1 row/wave, 4 px/thread.
__global__ __launch_bounds__(128) void pass1_kernel(const float* __restrict__ F,
                                                    float* __restrict__ m1) {
    const int t    = threadIdx.x;
    const int n    = blockIdx.x / (HH / RPB);
    const int h0   = (blockIdx.x % (HH / RPB)) * RPB;
    const int sub  = t >> 6;
    const int lane = t & 63;
    const int h    = h0 + sub;
    const int w0   = lane * 4;

    // Column value/mask tables: pixel i, tap kx -> index i+kx (14 entries)
    float xval[14], mval[14];
#pragma unroll
    for (int j = 0; j < 14; ++j) {
        int c = w0 + j - PADK;
        bool ok = (c >= 0 && c < WW);
        xval[j] = ok ? (float)c * INVD : 0.0f;
        mval[j] = ok ? 1.0f : 0.0f;
    }

    const float* fp = F + (size_t)n * KK * HW + (size_t)h * WW + w0;
    float ax0 = 0, ax1 = 0, ax2 = 0, ax3 = 0;
    float ay0 = 0, ay1 = 0, ay2 = 0, ay3 = 0;

    for (int ky = 0; ky < KF; ++ky) {
        int rr = h + ky - PADK;
        if (rr < 0 || rr >= HH) continue;        // wave-uniform
        float yv = (float)rr * INVD;
        const float* fr = fp + (size_t)(ky * KF) * HW;

        float4 fq[KF];                            // 11 independent loads in flight
#pragma unroll
        for (int kx = 0; kx < KF; ++kx)
            fq[kx] = *(const float4*)(fr + (size_t)kx * HW);

        float s0 = 0, s1 = 0, s2 = 0, s3 = 0;
#pragma unroll
        for (int kx = 0; kx < KF; ++kx) {
            float4 f = fq[kx];
            ax0 = fmaf(f.x, xval[kx],     ax0); s0 = fmaf(f.x, mval[kx],     s0);
            ax1 = fmaf(f.y, xval[kx + 1], ax1); s1 = fmaf(f.y, mval[kx + 1], s1);
            ax2 = fmaf(f.z, xval[kx + 2], ax2); s2 = fmaf(f.z, mval[kx + 2], s2);
            ax3 = fmaf(f.w, xval[kx + 3], ax3); s3 = fmaf(f.w, mval[kx + 3], s3);
        }
        ay0 = fmaf(yv, s0, ay0); ay1 = fmaf(yv, s1, ay1);
        ay2 = fmaf(yv, s2, ay2); ay3 = fmaf(yv, s3, ay3);
    }
    *(float4*)(m1 + (size_t)n * 2 * HW + (size_t)h * WW + w0)      = make_float4(ax0, ax1, ax2, ax3);
    *(float4*)(m1 + (size_t)n * 2 * HW + HW + (size_t)h * WW + w0) = make_float4(ay0, ay1, ay2, ay3);
}

// Pass 2 (+ optionally fused pass 1 for the other direction).
template <bool FUSE>
__global__ __launch_bounds__(128) void pass2_kernel(const float* __restrict__ F,
                                                    const float* __restrict__ m1in,
                                                    float* __restrict__ m1out,
                                                    float* __restrict__ partial) {
    __shared__ __align__(16) float tile[2 * TROWS * TW2];   // 25.7 KB
    __shared__ float wsum[2];

    const int t    = threadIdx.x;
    const int n    = blockIdx.x / (HH / RPB);
    const int h0   = (blockIdx.x % (HH / RPB)) * RPB;
    const int sub  = t >> 6;
    const int lane = t & 63;
    const int h    = h0 + sub;
    const int w0   = lane * 4;

    // Stage 12-row x 268-col x 2-ch m1in neighborhood into LDS.
    const float* mbase = m1in + (size_t)n * 2 * HW;
    for (int i = t; i < 2 * TROWS * TW2; i += 128) {
        int ch  = i / (TROWS * TW2);
        int rem = i - ch * (TROWS * TW2);
        int r   = rem / TW2;
        int c   = rem - r * TW2;
        int rr  = h0 + r - PADK;
        int cc  = c - PADK;
        float v = 0.0f;
        if (rr >= 0 && rr < HH && cc >= 0 && cc < WW)
            v = mbase[(size_t)ch * HW + rr * WW + cc];
        tile[i] = v;
    }
    __syncthreads();

    float xval[14], mval[14];
#pragma unroll
    for (int j = 0; j < 14; ++j) {
        int c = w0 + j - PADK;
        bool ok = (c >= 0 && c < WW);
        xval[j] = ok ? (float)c * INVD : 0.0f;
        mval[j] = ok ? 1.0f : 0.0f;
    }

    const float* fp = F + (size_t)n * KK * HW + (size_t)h * WW + w0;

    float a1x0 = 0, a1x1 = 0, a1x2 = 0, a1x3 = 0;
    float a1y0 = 0, a1y1 = 0, a1y2 = 0, a1y3 = 0;
    float a2x0 = 0, a2x1 = 0, a2x2 = 0, a2x3 = 0;
    float a2y0 = 0, a2y1 = 0, a2y2 = 0, a2y3 = 0;

    for (int ky = 0; ky < KF; ++ky) {
        int rr = h + ky - PADK;
        if (rr < 0 || rr >= HH) continue;        // wave-uniform; tile rows zero anyway
        float yv = (float)rr * INVD;
        const float* fr = fp + (size_t)(ky * KF) * HW;

        float4 fq[KF];                            // 11 independent global loads
#pragma unroll
        for (int kx = 0; kx < KF; ++kx)
            fq[kx] = *(const float4*)(fr + (size_t)kx * HW);

        // Register-cache the tile span: cols w0..w0+13 (use 14 of 16), both ch.
        const float* tx = tile + (sub + ky) * TW2 + w0;   // 16B aligned
        const float* ty = tx + TROWS * TW2;
        float cx[16], cy[16];
#pragma unroll
        for (int q = 0; q < 4; ++q) {
            *(float4*)(cx + 4 * q) = *(const float4*)(tx + 4 * q);
            *(float4*)(cy + 4 * q) = *(const float4*)(ty + 4 * q);
        }

        float s0 = 0, s1 = 0, s2 = 0, s3 = 0;
#pragma unroll
        for (int kx = 0; kx < KF; ++kx) {
            float4 f = fq[kx];
            if (FUSE) {
                a1x0 = fmaf(f.x, xval[kx],     a1x0); s0 = fmaf(f.x, mval[kx],     s0);
                a1x1 = fmaf(f.y, xval[kx + 1], a1x1); s1 = fmaf(f.y, mval[kx + 1], s1);
                a1x2 = fmaf(f.z, xval[kx + 2], a1x2); s2 = fmaf(f.z, mval[kx + 2], s2);
                a1x3 = fmaf(f.w, xval[kx + 3], a1x3); s3 = fmaf(f.w, mval[kx + 3], s3);
            }
            a2x0 = fmaf(f.x, cx[kx],     a2x0); a2y0 = fmaf(f.x, cy[kx],     a2y0);
            a2x1 = fmaf(f.y, cx[kx + 1], a2x1); a2y1 = fmaf(f.y, cy[kx + 1], a2y1);
            a2x2 = fmaf(f.z, cx[kx + 2], a2x2); a2y2 = fmaf(f.z, cy[kx + 2], a2y2);
            a2x3 = fmaf(f.w, cx[kx + 3], a2x3); a2y3 = fmaf(f.w, cy[kx + 3], a2y3);
        }
        if (FUSE) {
            a1y0 = fmaf(yv, s0, a1y0); a1y1 = fmaf(yv, s1, a1y1);
            a1y2 = fmaf(yv, s2, a1y2); a1y3 = fmaf(yv, s3, a1y3);
        }
    }

    if (FUSE) {
        *(float4*)(m1out + (size_t)n * 2 * HW + (size_t)h * WW + w0)      = make_float4(a1x0, a1x1, a1x2, a1x3);
        *(float4*)(m1out + (size_t)n * 2 * HW + HW + (size_t)h * WW + w0) = make_float4(a1y0, a1y1, a1y2, a1y3);
    }

    const float gy = (float)h * INVD;
    float d = 0.0f;
    {
        float gx0 = (float)w0 * INVD;
        float dx, dy;
        dx = gx0 - a2x0;              dy = gy - a2y0; d += sqrtf(dx * dx + dy * dy);
        dx = gx0 + INVD - a2x1;       dy = gy - a2y1; d += sqrtf(dx * dx + dy * dy);
        dx = gx0 + 2 * INVD - a2x2;   dy = gy - a2y2; d += sqrtf(dx * dx + dy * dy);
        dx = gx0 + 3 * INVD - a2x3;   dy = gy - a2y3; d += sqrtf(dx * dx + dy * dy);
    }

    // block reduce (2 waves) -> one partial per block
#pragma unroll
    for (int off = 32; off > 0; off >>= 1) d += __shfl_down(d, off, 64);
    if (lane == 0) wsum[sub] = d;
    __syncthreads();
    if (t == 0) partial[blockIdx.x] = wsum[0] + wsum[1];
}

__global__ __launch_bounds__(256) void finalize_kernel(const float* __restrict__ partial,
                                                       float* __restrict__ out) {
    __shared__ float wsum[4];
    int t = threadIdx.x;
    float s = partial[t] + partial[t + 256] + partial[t + 512] + partial[t + 768];
#pragma unroll
    for (int off = 32; off > 0; off >>= 1) s += __shfl_down(s, off, 64);
    if ((t & 63) == 0) wsum[t >> 6] = s;
    __syncthreads();
    if (t == 0)
        out[0] = (wsum[0] + wsum[1] + wsum[2] + wsum[3]) * (1.0f / ((float)HW * (float)NB));
}

extern "C" void kernel_launch(void* const* d_in, const int* in_sizes, int n_in,
                              void* d_out, int out_size, void* d_ws, size_t ws_size,
                              hipStream_t stream) {
    const float* FA = (const float*)d_in[0];  // FF_AtoB
    const float* FB = (const float*)d_in[1];  // FF_BtoA
    float* out = (float*)d_out;

    float* m1A = (float*)d_ws;                       // [N,2,H,W] = 2 MB
    float* m1B = m1A + (size_t)NB * 2 * HW;          // [N,2,H,W] = 2 MB
    float* partial = m1B + (size_t)NB * 2 * HW;      // 1024 floats, all rewritten

    dim3 grid(GRID1), block(128);
    // m1_ABA = flow(grid, F_AtoB)
    pass1_kernel<<<grid, block, 0, stream>>>(FA, m1A);
    // single read of F_BtoA serves BOTH m2_ABA (-> loss) and m1_BAB
    pass2_kernel<true><<<grid, block, 0, stream>>>(FB, m1A, m1B, partial);
    // m2_BAB = flow(m1_BAB, F_AtoB) -> loss (FA likely still L3-resident)
    pass2_kernel<false><<<grid, block, 0, stream>>>(FA, m1B, nullptr, partial + GRID1);

    finalize_kernel<<<1, dim3(256), 0, stream>>>(partial, out);
}

// Round 5
// 304.453 us; speedup vs baseline: 1.9953x; 1.0379x over previous
//
#include <hip/hip_runtime.h>
#include <math.h>

// Problem constants (fixed by setup_inputs): N=4, K=11, H=W=256.
#define NB    4
#define KF    11
#define KK    121
#define HH    256
#define WW    256
#define HW    (HH * WW)
#define HW2   (HW / 2)
#define PADK  5
#define RPB   2                    // rows per block (128 threads per row)
#define TROWS (RPB + KF - 1)       // 12 tile rows
#define TW2   268                  // padded tile width, multiple of 4 (16B align)
#define INVD  (1.0f / 255.0f)
#define GRID1 (NB * HH / RPB)      // 512 blocks x 256 thr = 8 waves/CU

// Pass 1: m1 = filter_flow(grid, F). 2 rows/block, 2 px/thread, float2 loads,
// ky-pair batching -> 22 outstanding loads per thread.
__global__ __launch_bounds__(256) void pass1_kernel(const float* __restrict__ F,
                                                    float* __restrict__ m1) {
    const int t   = threadIdx.x;
    const int n   = blockIdx.x / (HH / RPB);
    const int h0  = (blockIdx.x % (HH / RPB)) * RPB;
    const int sub = t >> 7;
    const int j   = t & 127;
    const int h   = h0 + sub;
    const int w0  = j * 2;

    float mk0[KF], mk1[KF];
#pragma unroll
    for (int kx = 0; kx < KF; ++kx) {
        int c0 = w0 + kx - PADK;
        mk0[kx] = (c0 >= 0 && c0 < WW) ? 1.0f : 0.0f;
        mk1[kx] = (c0 + 1 >= 0 && c0 + 1 < WW) ? 1.0f : 0.0f;
    }
    const float b0 = (float)(w0 - PADK) * INVD;

    const float2* fp = (const float2*)(F + (size_t)n * KK * HW + (size_t)h * WW + w0);

    float ax0 = 0, ax1 = 0, ay0 = 0, ay1 = 0;

    // valid ky range is contiguous (wave-uniform): rr = h + ky - PADK in [0,HH)
    const int lo = (h < PADK) ? (PADK - h) : 0;
    const int hi = (h > HH - 1 - PADK) ? (HH - 1 + PADK - h) : (KF - 1);

    auto comp = [&](const float2* fq, int ky) {
        float yv = (float)(h + ky - PADK) * INVD;
        float s0 = 0, s1 = 0;
#pragma unroll
        for (int kx = 0; kx < KF; ++kx) {
            float2 f = fq[kx];
            float xk = b0 + (float)kx * INVD;
            float u0 = f.x * mk0[kx], u1 = f.y * mk1[kx];
            ax0 = fmaf(u0, xk, ax0);
            ax1 = fmaf(u1, xk + INVD, ax1);
            s0 += u0; s1 += u1;
        }
        ay0 = fmaf(yv, s0, ay0);
        ay1 = fmaf(yv, s1, ay1);
    };

    int ky = lo;
    for (; ky + 1 <= hi; ky += 2) {
        float2 fqA[KF], fqB[KF];
        const float2* frA = fp + (size_t)(ky * KF) * HW2;
        const float2* frB = frA + (size_t)KF * HW2;
#pragma unroll
        for (int kx = 0; kx < KF; ++kx) fqA[kx] = frA[(size_t)kx * HW2];
#pragma unroll
        for (int kx = 0; kx < KF; ++kx) fqB[kx] = frB[(size_t)kx * HW2];
        comp(fqA, ky);
        comp(fqB, ky + 1);
    }
    if (ky <= hi) {
        float2 fqA[KF];
        const float2* frA = fp + (size_t)(ky * KF) * HW2;
#pragma unroll
        for (int kx = 0; kx < KF; ++kx) fqA[kx] = frA[(size_t)kx * HW2];
        comp(fqA, ky);
    }

    *(float2*)(m1 + (size_t)n * 2 * HW + (size_t)h * WW + w0)      = make_float2(ax0, ax1);
    *(float2*)(m1 + (size_t)n * 2 * HW + HW + (size_t)h * WW + w0) = make_float2(ay0, ay1);
}

// Pass 2 (+ optionally fused pass 1 for the other direction), ky-pair batched.
template <bool FUSE>
__global__ __launch_bounds__(256) void pass2_kernel(const float* __restrict__ F,
                                                    const float* __restrict__ m1in,
                                                    float* __restrict__ m1out,
                                                    float* __restrict__ partial) {
    __shared__ __align__(16) float tile[2 * TROWS * TW2];   // 25.7 KB
    __shared__ float wsum[4];

    const int t   = threadIdx.x;
    const int n   = blockIdx.x / (HH / RPB);
    const int h0  = (blockIdx.x % (HH / RPB)) * RPB;
    const int sub = t >> 7;
    const int j   = t & 127;
    const int h   = h0 + sub;
    const int w0  = j * 2;

    // Stage 12-row x 268-col x 2-ch m1in neighborhood into LDS (mostly L2-hot).
    const float* mbase = m1in + (size_t)n * 2 * HW;
    for (int i = t; i < 2 * TROWS * TW2; i += 256) {
        int ch  = i / (TROWS * TW2);
        int rem = i - ch * (TROWS * TW2);
        int r   = rem / TW2;
        int c   = rem - r * TW2;
        int rr  = h0 + r - PADK;
        int cc  = c - PADK;
        float v = 0.0f;
        if (rr >= 0 && rr < HH && cc >= 0 && cc < WW)
            v = mbase[(size_t)ch * HW + rr * WW + cc];
        tile[i] = v;
    }
    __syncthreads();

    float mk0[KF], mk1[KF];
    if (FUSE) {
#pragma unroll
        for (int kx = 0; kx < KF; ++kx) {
            int c0 = w0 + kx - PADK;
            mk0[kx] = (c0 >= 0 && c0 < WW) ? 1.0f : 0.0f;
            mk1[kx] = (c0 + 1 >= 0 && c0 + 1 < WW) ? 1.0f : 0.0f;
        }
    }
    const float b0 = (float)(w0 - PADK) * INVD;

    const float2* fp = (const float2*)(F + (size_t)n * KK * HW + (size_t)h * WW + w0);

    float a1x0 = 0, a1x1 = 0, a1y0 = 0, a1y1 = 0;
    float a2x0 = 0, a2x1 = 0, a2y0 = 0, a2y1 = 0;

    const int lo = (h < PADK) ? (PADK - h) : 0;
    const int hi = (h > HH - 1 - PADK) ? (HH - 1 + PADK - h) : (KF - 1);

    auto comp = [&](const float2* fq, int ky) {
        float yv = (float)(h + ky - PADK) * INVD;
        // Register-cache this ky's tile span: cols w0..w0+11, both channels.
        const float* tx = tile + (sub + ky) * TW2 + w0;   // 8B-aligned
        const float* ty = tx + TROWS * TW2;
        float cx[12], cy[12];
#pragma unroll
        for (int q = 0; q < 6; ++q) {
            float2 vx = *(const float2*)(tx + 2 * q);
            float2 vy = *(const float2*)(ty + 2 * q);
            cx[2 * q] = vx.x; cx[2 * q + 1] = vx.y;
            cy[2 * q] = vy.x; cy[2 * q + 1] = vy.y;
        }
        float s0 = 0, s1 = 0;
#pragma unroll
        for (int kx = 0; kx < KF; ++kx) {
            float2 f = fq[kx];
            if (FUSE) {
                float u0 = f.x * mk0[kx], u1 = f.y * mk1[kx];
                float xk = b0 + (float)kx * INVD;
                a1x0 = fmaf(u0, xk, a1x0);
                a1x1 = fmaf(u1, xk + INVD, a1x1);
                s0 += u0; s1 += u1;
            }
            a2x0 = fmaf(f.x, cx[kx], a2x0);
            a2x1 = fmaf(f.y, cx[kx + 1], a2x1);
            a2y0 = fmaf(f.x, cy[kx], a2y0);
            a2y1 = fmaf(f.y, cy[kx + 1], a2y1);
        }
        if (FUSE) {
            a1y0 = fmaf(yv, s0, a1y0);
            a1y1 = fmaf(yv, s1, a1y1);
        }
    };

    int ky = lo;
    for (; ky + 1 <= hi; ky += 2) {
        float2 fqA[KF], fqB[KF];
        const float2* frA = fp + (size_t)(ky * KF) * HW2;
        const float2* frB = frA + (size_t)KF * HW2;
#pragma unroll
        for (int kx = 0; kx < KF; ++kx) fqA[kx] = frA[(size_t)kx * HW2];
#pragma unroll
        for (int kx = 0; kx < KF; ++kx) fqB[kx] = frB[(size_t)kx * HW2];
        comp(fqA, ky);
        comp(fqB, ky + 1);
    }
    if (ky <= hi) {
        float2 fqA[KF];
        const float2* frA = fp + (size_t)(ky * KF) * HW2;
#pragma unroll
        for (int kx = 0; kx < KF; ++kx) fqA[kx] = frA[(size_t)kx * HW2];
        comp(fqA, ky);
    }

    if (FUSE) {
        *(float2*)(m1out + (size_t)n * 2 * HW + (size_t)h * WW + w0)      = make_float2(a1x0, a1x1);
        *(float2*)(m1out + (size_t)n * 2 * HW + HW + (size_t)h * WW + w0) = make_float2(a1y0, a1y1);
    }

    float gx = (float)w0 * INVD, gy = (float)h * INVD;
    float dx0 = gx - a2x0,        dy0 = gy - a2y0;
    float dx1 = gx + INVD - a2x1, dy1 = gy - a2y1;
    float d = sqrtf(dx0 * dx0 + dy0 * dy0) + sqrtf(dx1 * dx1 + dy1 * dy1);

    // block reduce -> one partial per block (no atomics, no zero-init needed)
#pragma unroll
    for (int off = 32; off > 0; off >>= 1) d += __shfl_down(d, off, 64);
    if ((t & 63) == 0) wsum[t >> 6] = d;
    __syncthreads();
    if (t == 0) partial[blockIdx.x] = wsum[0] + wsum[1] + wsum[2] + wsum[3];
}

__global__ __launch_bounds__(256) void finalize_kernel(const float* __restrict__ partial,
                                                       float* __restrict__ out) {
    __shared__ float wsum[4];
    int t = threadIdx.x;
    float s = partial[t] + partial[t + 256] + partial[t + 512] + partial[t + 768];
#pragma unroll
    for (int off = 32; off > 0; off >>= 1) s += __shfl_down(s, off, 64);
    if ((t & 63) == 0) wsum[t >> 6] = s;
    __syncthreads();
    if (t == 0)
        out[0] = (wsum[0] + wsum[1] + wsum[2] + wsum[3]) * (1.0f / ((float)HW * (float)NB));
}

extern "C" void kernel_launch(void* const* d_in, const int* in_sizes, int n_in,
                              void* d_out, int out_size, void* d_ws, size_t ws_size,
                              hipStream_t stream) {
    const float* FA = (const float*)d_in[0];  // FF_AtoB
    const float* FB = (const float*)d_in[1];  // FF_BtoA
    float* out = (float*)d_out;

    float* m1A = (float*)d_ws;                       // [N,2,H,W] = 2 MB
    float* m1B = m1A + (size_t)NB * 2 * HW;          // [N,2,H,W] = 2 MB
    float* partial = m1B + (size_t)NB * 2 * HW;      // 1024 floats, all rewritten

    dim3 grid(GRID1), block(256);
    // m1_ABA = flow(grid, F_AtoB)
    pass1_kernel<<<grid, block, 0, stream>>>(FA, m1A);
    // single read of F_BtoA serves BOTH m2_ABA (-> loss) and m1_BAB
    pass2_kernel<true><<<grid, block, 0, stream>>>(FB, m1A, m1B, partial);
    // m2_BAB = flow(m1_BAB, F_AtoB) -> loss (FA partially L3-resident)
    pass2_kernel<false><<<grid, block, 0, stream>>>(FA, m1B, nullptr, partial + GRID1);

    finalize_kernel<<<1, dim3(256), 0, stream>>>(partial, out);
}